// Round 4
// baseline (870.324 us; speedup 1.0000x reference)
//
#include <hip/hip_runtime.h>
#include <hip/hip_bf16.h>
#include <stdint.h>

typedef _Float16 f16;
typedef _Float16 f16x2 __attribute__((ext_vector_type(2)));
typedef _Float16 f16x4 __attribute__((ext_vector_type(4)));
typedef _Float16 f16x8 __attribute__((ext_vector_type(8)));
typedef float f32x4 __attribute__((ext_vector_type(4)));
typedef int   i32x4 __attribute__((ext_vector_type(4)));

#define T_STEPS 512
#define BATCH   128
#define DD      512
#define LOG2E   1.44269504088896f

// workspace layout (bytes)
#define XP_OFF  0                          // f16 Xproj' [512][128][512] = 67,108,864
#define WF_OFF  (67108864)                 // f16 W_in  [512][512]      =    524,288
#define WHQ_OFF (67108864 + 524288)        // i8  W_h frag-packed       =    262,144
#define SC_OFF  (67108864 + 524288 + 262144) // f32 row scales2 [512]   =      2,048

__device__ __forceinline__ f16x2 pk(float a, float b) {
    return __builtin_bit_cast(f16x2, __builtin_amdgcn_cvt_pkrtz(a, b));
}

__device__ __forceinline__ float fast_exp2(float x) {
#if __has_builtin(__builtin_amdgcn_exp2f)
    return __builtin_amdgcn_exp2f(x);
#else
    return exp2f(x);
#endif
}

__device__ __forceinline__ float fast_rcp(float x) {
#if __has_builtin(__builtin_amdgcn_rcpf)
    return __builtin_amdgcn_rcpf(x);
#else
    return 1.0f / x;
#endif
}

__device__ __forceinline__ uint32_t pack_u8(float s, int pos, uint32_t old) {
#if __has_builtin(__builtin_amdgcn_cvt_pk_u8_f32)
    return __builtin_amdgcn_cvt_pk_u8_f32(s, pos, old);
#else
    return old | (((uint32_t)(int)s & 0xFF) << (8 * pos));
#endif
}

#define GLDS(g, l) __builtin_amdgcn_global_load_lds(                               \
        (const __attribute__((address_space(1))) void*)(g),                        \
        (__attribute__((address_space(3))) void*)(l), 16, 0, 0)

// ---------------------------------------------------------------- prep: Wf (f16 W_in)
__global__ __launch_bounds__(256) void prep_kernel(
        const float* __restrict__ Win, f16* __restrict__ Wf) {
    int idx = blockIdx.x * 256 + threadIdx.x;
    if (idx < 262144) Wf[idx] = (f16)Win[idx];
}

// ------------------------------------------- quantize W_h to i8, frag-packed, per-row scale
// one wave per output row o. A-frag packing: byte index
//   ((rt*8+ks)*64 + l)*16 + j  ->  W_h[out][k],  rt = o>>4
//   out = rt*16+(l&15), k = ks*64+(l>>4)*16+j
// scales2[o] = -log2e * m/(127*127): epilogue computes t = acc*sc2 + xp2 = -log2e*v.
__global__ __launch_bounds__(64) void quant_kernel(
        const float* __restrict__ Wh, char* __restrict__ Whq, float* __restrict__ scales) {
    const int o = blockIdx.x, t = threadIdx.x;
    const float* row = Wh + (size_t)o * 512;
    float v[8];
    float m = 0.f;
#pragma unroll
    for (int j = 0; j < 8; j++) { v[j] = row[t * 8 + j]; m = fmaxf(m, fabsf(v[j])); }
#pragma unroll
    for (int off = 32; off > 0; off >>= 1) m = fmaxf(m, __shfl_xor(m, off));
    if (t == 0) scales[o] = -LOG2E * m * (1.0f / (127.0f * 127.0f));
    const float inv = 127.0f / m;
    const int rt = o >> 4, rl = o & 15;
    const int k0 = t * 8;
    const int ks = k0 >> 6, qq = (k0 >> 4) & 3, j0 = k0 & 15;
    const int l = qq * 16 + rl;
    char* dst = Whq + ((size_t)((rt * 8 + ks) * 64 + l)) * 16 + j0;
#pragma unroll
    for (int j = 0; j < 8; j++) dst[j] = (char)rintf(v[j] * inv);
}

// ------------------------------------------------- Xproj' = -log2e*(X @ Win^T + b_h), f16
// R4: 64M x 128N tile, 256 threads (4 waves: wm 0..1 x wn 0..1, per-wave 32x64), BK=32,
// double-buffered GLDS. 4 blocks/CU = 4 INDEPENDENT barrier domains per CU -> one block's
// prefetch latency (vmcnt(0) drain at its barrier) hides under other blocks' compute —
// attacks the lockstep serialization that kept 3 structurally different gemms at ~200us.
// Swizzles identical to R3 (verified): A f=row&7 (f32 16B chunks), B f=(row>>1)&3 (f16);
// both valid for any row-base that is a multiple of 8. XCD swizzle keeps the 4 n-blocks
// of one A-panel consecutive on one XCD (A L2-hit). ~85 VGPR, no spill at cap 128.
__global__ __launch_bounds__(256, 4) void gemm_kernel(
        const float* __restrict__ X, const f16* __restrict__ Wf,
        const float* __restrict__ bias, f16* __restrict__ Xp) {
    const int tid = threadIdx.x;
    const int l = tid & 63, w = tid >> 6;       // w 0..3
    const int q = l >> 4, rl = l & 15;
    const int wm = w >> 1, wn = w & 1;
    const int blk = blockIdx.x;                 // 0..4095
    const int xcd = blk & 7, idx = blk >> 3;    // idx 0..511
    const int m_blk = (xcd * 128 + (idx >> 2)) * 64;
    const int n_blk = (idx & 3) * 128;

    __shared__ __align__(16) float As[2][64 * 32];    // 2 x 8 KB
    __shared__ __align__(16) f16   Bs[2][128 * 32];   // 2 x 8 KB

    // A staging: instr c in {0,1}: row = w*16 + c*8 + (l>>3); src chunk = (l&7)^(l>>3)
    const float* aSrc[2];
#pragma unroll
    for (int c = 0; c < 2; c++)
        aSrc[c] = X + (size_t)(m_blk + w * 16 + c * 8 + (l >> 3)) * 512
                    + (((l & 7) ^ (l >> 3)) << 2);
    // B staging: instr c in {0,1}: row = c*64 + w*16 + (l>>2); src chunk = (l&3)^((l>>3)&3)
    const f16* bSrc[2];
#pragma unroll
    for (int c = 0; c < 2; c++)
        bSrc[c] = Wf + (size_t)(n_blk + c * 64 + w * 16 + (l >> 2)) * 512
                     + (((l & 3) ^ ((l >> 3) & 3)) << 3);

    f32x4 acc[2][4] = {};
    const int swA0 = (((2 * q)     ^ (rl & 7)) << 2);        // float units
    const int swA1 = (((2 * q + 1) ^ (rl & 7)) << 2);
    const int swB  = ((q ^ ((rl >> 1) & 3)) << 3);           // f16 units

    // prologue: stage tile 0
#pragma unroll
    for (int c = 0; c < 2; c++) GLDS(aSrc[c], &As[0][(w * 16 + c * 8) * 32]);
#pragma unroll
    for (int c = 0; c < 2; c++) GLDS(bSrc[c], &Bs[0][(c * 64 + w * 16) * 32]);

    for (int t = 0; t < 16; ++t) {
        const int cur = t & 1;
        __syncthreads();   // tile cur ready; all waves done reading cur^1
        if (t < 15) {
            const int kf = (t + 1) * 32;
#pragma unroll
            for (int c = 0; c < 2; c++) GLDS(aSrc[c] + kf, &As[cur ^ 1][(w * 16 + c * 8) * 32]);
#pragma unroll
            for (int c = 0; c < 2; c++) GLDS(bSrc[c] + kf, &Bs[cur ^ 1][(c * 64 + w * 16) * 32]);
        }
        f16x8 af4[2], bf4[4];
#pragma unroll
        for (int i = 0; i < 2; i++) {
            const int row = wm * 32 + i * 16 + rl;
            const float4 h0 = *(const float4*)&As[cur][row * 32 + swA0];
            const float4 h1 = *(const float4*)&As[cur][row * 32 + swA1];
            f16x2 p0 = pk(h0.x, h0.y), p1 = pk(h0.z, h0.w);
            f16x2 p2 = pk(h1.x, h1.y), p3 = pk(h1.z, h1.w);
            f16x8 tv;
            tv[0] = p0[0]; tv[1] = p0[1]; tv[2] = p1[0]; tv[3] = p1[1];
            tv[4] = p2[0]; tv[5] = p2[1]; tv[6] = p3[0]; tv[7] = p3[1];
            af4[i] = tv;
        }
#pragma unroll
        for (int j = 0; j < 4; j++) {
            const int row = wn * 64 + j * 16 + rl;
            bf4[j] = *(const f16x8*)&Bs[cur][row * 32 + swB];
        }
        // swapped operands: D row = n (q*4+r), D col = m (rl)
#pragma unroll
        for (int i = 0; i < 2; i++)
#pragma unroll
            for (int j = 0; j < 4; j++)
                acc[i][j] = __builtin_amdgcn_mfma_f32_16x16x32_f16(bf4[j], af4[i], acc[i][j], 0, 0, 0);
    }
    // epilogue: lane holds, for (i,j): n = n_blk+wn*64+j*16+q*4+r, m = m_blk+wm*32+i*16+rl
#pragma unroll
    for (int j = 0; j < 4; j++) {
        const float4 b4 = *(const float4*)&bias[n_blk + wn * 64 + j * 16 + q * 4];
        const float bb[4] = {b4.x, b4.y, b4.z, b4.w};
#pragma unroll
        for (int i = 0; i < 2; i++) {
            const int m = m_blk + wm * 32 + i * 16 + rl;
            f16x4 v;
#pragma unroll
            for (int r = 0; r < 4; r++)
                v[r] = (f16)(-LOG2E * (acc[i][j][r] + bb[r]));   // scalar cast: RTE
            *(f16x4*)(Xp + (size_t)m * 512 + n_blk + wn * 64 + j * 16 + q * 4) = v;
        }
    }
}

// ----------------------------------------------------------------- recurrence (i8 MFMA)
// R4: 8 waves (512 thr), wave w owns 64 rows (4 row-tiles). Rationale: each wave MUST read
// the full 8KB h-fragment buffer (B-frag is wave-private), so per-CU LDS traffic = waves x
// 8KB. 16 waves -> 128KB/step (~1024+ cyc floor, R3 measured 2170); 8 waves -> 64KB
// (~512-768 cyc). R0 failed at this shape because its epilogue was fully serialized after
// all 32 MFMAs; here: bfr[8] up-front, 4 phase-split chains, epilogue-mt between chains
// (overlaps chain-mt+1 on VALU/trans pipes), setprio(1) on chains only.
// VGPR: af 128 + bfr 32 + state ~60 = ~220 <= 256 (2 waves/SIMD).
__global__ __launch_bounds__(512, 2) void rnn_kernel(
        const char* __restrict__ Whq, const float* __restrict__ scales,
        const f16* __restrict__ Xp, float* __restrict__ out) {
    const int wg = blockIdx.x;          // 0..7
    const int tid = threadIdx.x;
    const int l = tid & 63, w = tid >> 6;   // w in 0..7
    const int bl = l & 15;              // batch lane (N / C col)
    const int q = l >> 4;               // k-quad / C row quad
    const int b = wg * 16 + bl;

    __shared__ __align__(16) uint32_t hT[2][2048];   // 8 KB per buffer, frag-ordered

    // register-resident i8 A-fragments: af[mt][ks], 4 dwords each = 128 regs
    i32x4 af[4][8];
    {
        const i32x4* wp = (const i32x4*)Whq;
#pragma unroll
        for (int mt = 0; mt < 4; mt++)
#pragma unroll
            for (int ks = 0; ks < 8; ks++)
                af[mt][ks] = wp[((w * 4 + mt) * 8 + ks) * 64 + l];
    }
    // per-lane output-row scales (pre-folded with -log2e/127^2)
    float sc[4][4];
#pragma unroll
    for (int mt = 0; mt < 4; mt++)
#pragma unroll
        for (int r = 0; r < 4; r++)
            sc[mt][r] = scales[w * 64 + mt * 16 + q * 4 + r];

    for (int i = tid; i < 2048; i += 512) hT[0][i] = 0u;
    __syncthreads();

    const f16* xpb = Xp + (size_t)b * 512 + w * 64 + q * 4;
    f16x4 xn[4];
#pragma unroll
    for (int mt = 0; mt < 4; mt++) xn[mt] = *(const f16x4*)(xpb + mt * 16);

    const float K127 = 1.0f / 127.0f;
    for (int t = 0; t < T_STEPS; t++) {
        f16x4 xc[4];
#pragma unroll
        for (int mt = 0; mt < 4; mt++) xc[mt] = xn[mt];
        const size_t tn = (size_t)(t < T_STEPS - 1 ? t + 1 : t) * (BATCH * 512);
#pragma unroll
        for (int mt = 0; mt < 4; mt++) xn[mt] = *(const f16x4*)(xpb + tn + mt * 16);

        const int rb = t & 1;
        const uint32_t* hrow = &hT[rb][l * 4];
        uint32_t* hwr = &hT[1 - rb][w * 256 + bl * 4 + q];

        // single read stream: 8 b128 into regs, reused by all 4 chains
        i32x4 bfr[8];
#pragma unroll
        for (int ks = 0; ks < 8; ks++)
            bfr[ks] = *(const i32x4*)(hrow + ks * 256);

        // 4 phase-split chains; epilogue mt overlaps chain mt+1 (independent pipes)
#pragma unroll
        for (int mt = 0; mt < 4; mt++) {
            i32x4 acc = {};
            __builtin_amdgcn_s_setprio(1);
#pragma unroll
            for (int ks = 0; ks < 8; ks++)
                acc = __builtin_amdgcn_mfma_i32_16x16x64_i8(af[mt][ks], bfr[ks], acc, 0, 0, 0);
            __builtin_amdgcn_s_setprio(0);
            uint32_t pkq = 0;
#pragma unroll
            for (int r = 0; r < 4; r++) {
                float tt = fmaf((float)acc[r], sc[mt][r], (float)xc[mt][r]);
                float e  = fast_exp2(tt);                // e^{-v}
                float eq = fmaf(e, K127, K127);          // (1+e^{-v})/127
                float sg = fast_rcp(eq) + 0.5f;          // 127*sigmoid + 0.5
                pkq = pack_u8(sg, r, pkq);
            }
            hwr[mt * 64] = pkq;
        }
        __syncthreads();
    }
    // final h: read back this lane's own dwords, dequantize i8/127 -> f32
#pragma unroll
    for (int mt = 0; mt < 4; mt++) {
        uint32_t pkq = hT[T_STEPS & 1][w * 256 + (mt * 16 + bl) * 4 + q];
        float4 o;
        o.x = (float)((pkq      ) & 0xFF) * K127;
        o.y = (float)((pkq >>  8) & 0xFF) * K127;
        o.z = (float)((pkq >> 16) & 0xFF) * K127;
        o.w = (float)((pkq >> 24) & 0xFF) * K127;
        *(float4*)(out + (size_t)b * 512 + w * 64 + mt * 16 + q * 4) = o;
    }
}

extern "C" void kernel_launch(void* const* d_in, const int* in_sizes, int n_in,
                              void* d_out, int out_size, void* d_ws, size_t ws_size,
                              hipStream_t stream) {
    const float* X   = (const float*)d_in[0];
    const float* Win = (const float*)d_in[1];
    const float* Wh  = (const float*)d_in[2];
    const float* bh  = (const float*)d_in[3];
    float* out = (float*)d_out;
    char* ws = (char*)d_ws;
    f16* Xp      = (f16*)(ws + XP_OFF);
    f16* Wf      = (f16*)(ws + WF_OFF);
    char* Whq    = (char*)(ws + WHQ_OFF);
    float* Sc    = (float*)(ws + SC_OFF);

    prep_kernel<<<1024, 256, 0, stream>>>(Win, Wf);
    quant_kernel<<<512, 64, 0, stream>>>(Wh, Whq, Sc);
    gemm_kernel<<<4096, 256, 0, stream>>>(X, Wf, bh, Xp);
    rnn_kernel<<<8, 512, 0, stream>>>(Whq, Sc, Xp, out);
}

// Round 5
// 700.943 us; speedup vs baseline: 1.2416x; 1.2416x over previous
//
#include <hip/hip_runtime.h>
#include <hip/hip_bf16.h>
#include <stdint.h>

typedef _Float16 f16;
typedef _Float16 f16x2 __attribute__((ext_vector_type(2)));
typedef _Float16 f16x4 __attribute__((ext_vector_type(4)));
typedef _Float16 f16x8 __attribute__((ext_vector_type(8)));
typedef float f32x4 __attribute__((ext_vector_type(4)));
typedef int   i32x4 __attribute__((ext_vector_type(4)));

#define T_STEPS 512
#define BATCH   128
#define DD      512
#define LOG2E   1.44269504088896f

// workspace layout (bytes)
#define XP_OFF  0                          // f16 Xproj' [512][128][512] = 67,108,864
#define WF_OFF  (67108864)                 // f16 W_in  [512][512]      =    524,288
#define WHQ_OFF (67108864 + 524288)        // i8  W_h frag-packed       =    262,144
#define SC_OFF  (67108864 + 524288 + 262144) // f32 row scales2 [512]   =      2,048

__device__ __forceinline__ f16x2 pk(float a, float b) {
    return __builtin_bit_cast(f16x2, __builtin_amdgcn_cvt_pkrtz(a, b));
}

__device__ __forceinline__ float fast_exp2(float x) {
#if __has_builtin(__builtin_amdgcn_exp2f)
    return __builtin_amdgcn_exp2f(x);
#else
    return exp2f(x);
#endif
}

__device__ __forceinline__ float fast_rcp(float x) {
#if __has_builtin(__builtin_amdgcn_rcpf)
    return __builtin_amdgcn_rcpf(x);
#else
    return 1.0f / x;
#endif
}

__device__ __forceinline__ uint32_t pack_u8(float s, int pos, uint32_t old) {
#if __has_builtin(__builtin_amdgcn_cvt_pk_u8_f32)
    return __builtin_amdgcn_cvt_pk_u8_f32(s, pos, old);
#else
    return old | (((uint32_t)(int)s & 0xFF) << (8 * pos));
#endif
}

#define GLDS(g, l) __builtin_amdgcn_global_load_lds(                               \
        (const __attribute__((address_space(1))) void*)(g),                        \
        (__attribute__((address_space(3))) void*)(l), 16, 0, 0)

// ---------------------------------------------------------------- prep: Wf (f16 W_in)
__global__ __launch_bounds__(256) void prep_kernel(
        const float* __restrict__ Win, f16* __restrict__ Wf) {
    int idx = blockIdx.x * 256 + threadIdx.x;
    if (idx < 262144) Wf[idx] = (f16)Win[idx];
}

// ------------------------------------------- quantize W_h to i8, frag-packed, per-row scale
// one wave per output row o. A-frag packing: byte index
//   ((rt*8+ks)*64 + l)*16 + j  ->  W_h[out][k],  rt = o>>4
//   out = rt*16+(l&15), k = ks*64+(l>>4)*16+j
// scales2[o] = -log2e * m/(127*127): epilogue computes t = acc*sc2 + xp2 = -log2e*v.
__global__ __launch_bounds__(64) void quant_kernel(
        const float* __restrict__ Wh, char* __restrict__ Whq, float* __restrict__ scales) {
    const int o = blockIdx.x, t = threadIdx.x;
    const float* row = Wh + (size_t)o * 512;
    float v[8];
    float m = 0.f;
#pragma unroll
    for (int j = 0; j < 8; j++) { v[j] = row[t * 8 + j]; m = fmaxf(m, fabsf(v[j])); }
#pragma unroll
    for (int off = 32; off > 0; off >>= 1) m = fmaxf(m, __shfl_xor(m, off));
    if (t == 0) scales[o] = -LOG2E * m * (1.0f / (127.0f * 127.0f));
    const float inv = 127.0f / m;
    const int rt = o >> 4, rl = o & 15;
    const int k0 = t * 8;
    const int ks = k0 >> 6, qq = (k0 >> 4) & 3, j0 = k0 & 15;
    const int l = qq * 16 + rl;
    char* dst = Whq + ((size_t)((rt * 8 + ks) * 64 + l)) * 16 + j0;
#pragma unroll
    for (int j = 0; j < 8; j++) dst[j] = (char)rintf(v[j] * inv);
}

// ------------------------------------------------- Xproj' = -log2e*(X @ Win^T + b_h), f16
// R5: 128M x 256N tile, BK=32, 8 waves (wm 0..1 x wn 0..3, per-wave 64x64, acc[4][4]).
// THE fix vs R1-R4: 3-buffer pipeline with COUNTED vmcnt across raw s_barrier (T3/T4).
// Every prior version drained vmcnt(0) at each __syncthreads -> full ~900cy HBM latency
// exposed per K-iter (the invariant behind 4 gemm shapes all stuck at 190-260us).
// Here: tile t+2 staged AFTER barrier(t); wait vmcnt(4) (tile t+1's 4 loads stay in
// flight) before barrier. Slack for a tile = ~2 iters > HBM latency.
// Safety: stage(t+2->buf[(t-1)%3]) issues only after barrier(t), which all iter-(t-1)
// readers passed; reads of tile t gated by own vmcnt(4)+barrier. One barrier/iter.
// Swizzles identical to R1 (verified): A f=row&7 (16B chunks), B f=(row>>1)&3.
// XCD swizzle: both n-tiles of an A-panel consecutive on one XCD (A L2-hit).
__global__ __launch_bounds__(512, 2) void gemm_kernel(
        const float* __restrict__ X, const f16* __restrict__ Wf,
        const float* __restrict__ bias, f16* __restrict__ Xp) {
    const int tid = threadIdx.x;
    const int l = tid & 63, w = tid >> 6;
    const int q = l >> 4, rl = l & 15;
    const int wm = w >> 2, wn = w & 3;
    const int blk = blockIdx.x;                 // 0..1023
    const int xcd = blk & 7, idx = blk >> 3;    // idx 0..127
    const int m_blk = (xcd * 64 + (idx >> 1)) * 128;
    const int n_blk = (idx & 1) * 256;

    __shared__ __align__(16) float As[3][128 * 32];   // 3 x 16 KB
    __shared__ __align__(16) f16   Bs[3][256 * 32];   // 3 x 16 KB

    // A staging: instr c in {0,1}: row = w*16 + c*8 + (l>>3); src chunk = (l&7)^(l>>3)
    const float* aSrc[2];
#pragma unroll
    for (int c = 0; c < 2; c++)
        aSrc[c] = X + (size_t)(m_blk + w * 16 + c * 8 + (l >> 3)) * 512
                    + (((l & 7) ^ (l >> 3)) << 2);
    // B staging: instr c in {0,1}: row = c*128 + w*16 + (l>>2); src chunk = (l&3)^((l>>3)&3)
    const f16* bSrc[2];
#pragma unroll
    for (int c = 0; c < 2; c++)
        bSrc[c] = Wf + (size_t)(n_blk + c * 128 + w * 16 + (l >> 2)) * 512
                     + (((l & 3) ^ ((l >> 3) & 3)) << 3);

#define STAGE(kt, sel) do {                                                        \
        const int kf_ = (kt) * 32;                                                 \
        GLDS(aSrc[0] + kf_, &As[sel][(w * 16 + 0) * 32]);                          \
        GLDS(aSrc[1] + kf_, &As[sel][(w * 16 + 8) * 32]);                          \
        GLDS(bSrc[0] + kf_, &Bs[sel][(0 * 128 + w * 16) * 32]);                    \
        GLDS(bSrc[1] + kf_, &Bs[sel][(1 * 128 + w * 16) * 32]);                    \
    } while (0)

    f32x4 acc[4][4] = {};
    const int swA0 = (((2 * q)     ^ (rl & 7)) << 2);        // float units
    const int swA1 = (((2 * q + 1) ^ (rl & 7)) << 2);
    const int swB  = ((q ^ ((rl >> 1) & 3)) << 3);           // f16 units

    // prologue: tiles 0 and 1 in flight (8 loads/wave)
    STAGE(0, 0);
    STAGE(1, 1);

#pragma unroll
    for (int t = 0; t < 16; ++t) {
        const int cur = t % 3;
        // retire own tile-t loads; keep tile t+1's 4 in flight across the barrier
        if (t < 15) asm volatile("s_waitcnt vmcnt(4)" ::: "memory");
        else        asm volatile("s_waitcnt vmcnt(0)" ::: "memory");
        __builtin_amdgcn_s_barrier();
        if (t + 2 < 16) STAGE(t + 2, (t + 2) % 3);

        f16x8 af4[4], bf4[4];
#pragma unroll
        for (int i = 0; i < 4; i++) {
            const int row = wm * 64 + i * 16 + rl;
            const float4 h0 = *(const float4*)&As[cur][row * 32 + swA0];
            const float4 h1 = *(const float4*)&As[cur][row * 32 + swA1];
            f16x2 p0 = pk(h0.x, h0.y), p1 = pk(h0.z, h0.w);
            f16x2 p2 = pk(h1.x, h1.y), p3 = pk(h1.z, h1.w);
            f16x8 tv;
            tv[0] = p0[0]; tv[1] = p0[1]; tv[2] = p1[0]; tv[3] = p1[1];
            tv[4] = p2[0]; tv[5] = p2[1]; tv[6] = p3[0]; tv[7] = p3[1];
            af4[i] = tv;
        }
#pragma unroll
        for (int j = 0; j < 4; j++) {
            const int row = wn * 64 + j * 16 + rl;
            bf4[j] = *(const f16x8*)&Bs[cur][row * 32 + swB];
        }
        // swapped operands: D row = n (q*4+r), D col = m (rl)
#pragma unroll
        for (int i = 0; i < 4; i++)
#pragma unroll
            for (int j = 0; j < 4; j++)
                acc[i][j] = __builtin_amdgcn_mfma_f32_16x16x32_f16(bf4[j], af4[i], acc[i][j], 0, 0, 0);
    }
#undef STAGE
    // epilogue: lane holds, for (i,j): n = n_blk+wn*64+j*16+q*4+r, m = m_blk+wm*64+i*16+rl
#pragma unroll
    for (int j = 0; j < 4; j++) {
        const float4 b4 = *(const float4*)&bias[n_blk + wn * 64 + j * 16 + q * 4];
        const float bb[4] = {b4.x, b4.y, b4.z, b4.w};
#pragma unroll
        for (int i = 0; i < 4; i++) {
            const int m = m_blk + wm * 64 + i * 16 + rl;
            f16x4 v;
#pragma unroll
            for (int r = 0; r < 4; r++)
                v[r] = (f16)(-LOG2E * (acc[i][j][r] + bb[r]));   // scalar cast: RTE
            *(f16x4*)(Xp + (size_t)m * 512 + n_blk + wn * 64 + j * 16 + q * 4) = v;
        }
    }
}

// ----------------------------------------------------------------- recurrence (i8 MFMA)
// EXACT R1 structure (best measured: 450us). 8 WGs x 16 batches; 16 waves (1024 thr),
// wave w owns row-tiles {2w, 2w+1}. ks-outer loop: ds_read bfr[ks] then 2 MFMAs, so LDS
// reads spread through the MFMA stream. 4 waves/SIMD hides epilogue/ds latency.
// Floors per CU/step: MFMA 1306cy, LDS 1024cy, VALU ~1000cy -> measured 2110cy.
// R2 (split phases, 2x reads) and R4 (8 waves) both regressed; do not revisit.
__global__ __launch_bounds__(1024) void rnn_kernel(
        const char* __restrict__ Whq, const float* __restrict__ scales,
        const f16* __restrict__ Xp, float* __restrict__ out) {
    const int wg = blockIdx.x;          // 0..7
    const int tid = threadIdx.x;
    const int l = tid & 63, w = tid >> 6;   // w in 0..15
    const int bl = l & 15;              // batch lane (N / C col)
    const int q = l >> 4;               // k-quad / C row quad
    const int b = wg * 16 + bl;

    __shared__ __align__(16) uint32_t hT[2][2048];   // 8 KB per buffer, frag-ordered

    // register-resident i8 A-fragments: af[mt][ks], 4 dwords each = 64 regs
    i32x4 af[2][8];
    {
        const i32x4* wp = (const i32x4*)Whq;
#pragma unroll
        for (int mt = 0; mt < 2; mt++)
#pragma unroll
            for (int ks = 0; ks < 8; ks++)
                af[mt][ks] = wp[((w * 2 + mt) * 8 + ks) * 64 + l];
    }
    // per-lane output-row scales (pre-folded with -log2e/127^2)
    float sc[2][4];
#pragma unroll
    for (int mt = 0; mt < 2; mt++)
#pragma unroll
        for (int r = 0; r < 4; r++)
            sc[mt][r] = scales[w * 32 + mt * 16 + q * 4 + r];

    for (int i = tid; i < 2048; i += 1024) hT[0][i] = 0u;
    __syncthreads();

    const f16* xpb = Xp + (size_t)b * 512 + w * 32 + q * 4;
    f16x4 xn0 = *(const f16x4*)(xpb);
    f16x4 xn1 = *(const f16x4*)(xpb + 16);

    const float K127 = 1.0f / 127.0f;
    for (int t = 0; t < T_STEPS; t++) {
        f16x4 xc0 = xn0, xc1 = xn1;
        const size_t tn = (size_t)(t < T_STEPS - 1 ? t + 1 : t) * (BATCH * 512);
        xn0 = *(const f16x4*)(xpb + tn);
        xn1 = *(const f16x4*)(xpb + tn + 16);

        const int rb = t & 1;
        i32x4 acc[2] = {};
        const uint32_t* hrow = &hT[rb][l * 4];
#pragma unroll
        for (int ks = 0; ks < 8; ks++) {
            i32x4 bfr = *(const i32x4*)(hrow + ks * 256);
            acc[0] = __builtin_amdgcn_mfma_i32_16x16x64_i8(af[0][ks], bfr, acc[0], 0, 0, 0);
            acc[1] = __builtin_amdgcn_mfma_i32_16x16x64_i8(af[1][ks], bfr, acc[1], 0, 0, 0);
        }
#pragma unroll
        for (int mt = 0; mt < 2; mt++) {
            uint32_t pkq = 0;
#pragma unroll
            for (int r = 0; r < 4; r++) {
                float tt = fmaf((float)acc[mt][r], sc[mt][r], (float)(mt == 0 ? xc0[r] : xc1[r]));
                float e  = fast_exp2(tt);                // e^{-v}
                float eq = fmaf(e, K127, K127);          // (1+e^{-v})/127
                float sg = fast_rcp(eq) + 0.5f;          // 127*sigmoid + 0.5
                pkq = pack_u8(sg, r, pkq);
            }
            hT[1 - rb][(w * 2 + mt) * 64 + bl * 4 + q] = pkq;
        }
        __syncthreads();
    }
    // final h: read back this lane's own dwords, dequantize i8/127 -> f32
#pragma unroll
    for (int mt = 0; mt < 2; mt++) {
        uint32_t pkq = hT[T_STEPS & 1][(w * 2 + mt) * 64 + bl * 4 + q];
        float4 o;
        o.x = (float)((pkq      ) & 0xFF) * K127;
        o.y = (float)((pkq >>  8) & 0xFF) * K127;
        o.z = (float)((pkq >> 16) & 0xFF) * K127;
        o.w = (float)((pkq >> 24) & 0xFF) * K127;
        *(float4*)(out + (size_t)b * 512 + w * 32 + mt * 16 + q * 4) = o;
    }
}

extern "C" void kernel_launch(void* const* d_in, const int* in_sizes, int n_in,
                              void* d_out, int out_size, void* d_ws, size_t ws_size,
                              hipStream_t stream) {
    const float* X   = (const float*)d_in[0];
    const float* Win = (const float*)d_in[1];
    const float* Wh  = (const float*)d_in[2];
    const float* bh  = (const float*)d_in[3];
    float* out = (float*)d_out;
    char* ws = (char*)d_ws;
    f16* Xp      = (f16*)(ws + XP_OFF);
    f16* Wf      = (f16*)(ws + WF_OFF);
    char* Whq    = (char*)(ws + WHQ_OFF);
    float* Sc    = (float*)(ws + SC_OFF);

    prep_kernel<<<1024, 256, 0, stream>>>(Win, Wf);
    quant_kernel<<<512, 64, 0, stream>>>(Wh, Whq, Sc);
    gemm_kernel<<<1024, 512, 0, stream>>>(X, Wf, bh, Xp);
    rnn_kernel<<<8, 1024, 0, stream>>>(Whq, Sc, Xp, out);
}